// Round 6
// baseline (312.262 us; speedup 1.0000x reference)
//
#include <hip/hip_runtime.h>

// out = wpw · depthwise3x3( bilinear_up(x) ), fp32 in/out
// A) dw (bilinear+dwconv folded) -> bf16 [b][px 19200][c 256] in d_ws
// B) out = wpw · dw  (LDS-free MFMA GEMM; B-frags loaded straight from global)
#define CIN  256
#define HIN  60
#define WIN  80
#define UPH  120
#define UPW  160
#define COUT 128
#define NPIX 19200

typedef __bf16 bf16x8 __attribute__((ext_vector_type(8)));
typedef float  floatx4 __attribute__((ext_vector_type(4)));

__device__ inline uint32_t pack_bf2(float lo, float hi) {
    union { __bf16 h; unsigned short s; } a, b;
    a.h = (__bf16)lo; b.h = (__bf16)hi;
    return (uint32_t)a.s | ((uint32_t)b.s << 16);
}
__device__ inline float unp_lo(uint32_t w) { return __uint_as_float(w << 16); }
__device__ inline float unp_hi(uint32_t w) { return __uint_as_float(w & 0xFFFF0000u); }

// ======================= Kernel A: depthwise producer =======================
// block: 32 ch x 4 out-rows x 160 cols; 320 thr; thread = (chpair, 8-px run).
// s_px word (r,chp,c) = (bf16 x[ch0][r][c], bf16 x[ch1][r][c]).
#define A_NT  320
#define A_SOS 20     // s_out px stride (words); 80 B -> 16B-aligned b128 reads

__global__ __launch_bounds__(A_NT, 3) void dw_kernel(
    const float* __restrict__ x,     // [B,256,60,80]
    const float* __restrict__ wdw,   // [256,1,3,3]
    __bf16* __restrict__ dwb,        // [bs,19200,256]
    int b0)
{
    __shared__ uint32_t s_px[5 * 16 * 84];    // 26.9 KB
    __shared__ float    s_A[32 * 49];         // 6.3 KB: [ch][h*12 + dy*4 + j]
    __shared__ uint32_t s_out[160 * A_SOS];   // 12.8 KB: one out-row, [px][chp]

    const int tid = threadIdx.x;
    const int h0  = blockIdx.x * 4;           // 0..116
    const int cb  = blockIdx.y * 32;
    const int bl  = blockIdx.z;
    const int b   = b0 + bl;

    const float HS = 59.0f / 121.0f;
    const float WS = 79.0f / 161.0f;
    const int rbase = (int)(h0 * HS);

    // ---- stage x as ch-pair words: unit=(chp,r), 4 threads x 20 cols ----
    {
        const int u = tid >> 2;               // 0..79
        const int part = tid & 3;
        const int chp_s = u / 5;
        const int r_s = u - chp_s * 5;
        const int gy = min(rbase + r_s, HIN - 1);
        const float* r0 = x + ((size_t)(b * CIN + cb + 2 * chp_s)) * (HIN * WIN)
                            + gy * WIN + part * 20;
        const float* r1 = r0 + HIN * WIN;
        uint32_t* dst = &s_px[(r_s * 16 + chp_s) * 84 + part * 20];
        float l0 = 0.f, l1 = 0.f;
        #pragma unroll
        for (int q = 0; q < 5; q++) {
            float4 v0 = *(const float4*)(r0 + q * 4);
            float4 v1 = *(const float4*)(r1 + q * 4);
            dst[q * 4 + 0] = pack_bf2(v0.x, v1.x);
            dst[q * 4 + 1] = pack_bf2(v0.y, v1.y);
            dst[q * 4 + 2] = pack_bf2(v0.z, v1.z);
            dst[q * 4 + 3] = pack_bf2(v0.w, v1.w);
            l0 = v0.w; l1 = v1.w;
        }
        if (part == 3) dst[20] = pack_bf2(l0, l1);   // col 80 = clamp(x[79])
    }
    // ---- fold dw kernel with row-interp weights ----
    for (int i = tid; i < 32 * 4 * 9; i += A_NT) {
        int ch  = i / 36;
        int rem = i - ch * 36;
        int h   = rem / 9;
        int dyj = rem - h * 9;
        int dy  = dyj / 3;
        int j   = dyj - dy * 3;
        int ybh = (int)((h0 + h) * HS);
        float acc = 0.f;
        #pragma unroll
        for (int i3 = 0; i3 < 3; i3++) {
            float hy = (h0 + h + i3) * HS;
            int y0 = (int)hy;
            float fy = hy - (float)y0;
            int y1 = min(y0 + 1, HIN - 1);
            float wgt = ((y0 - ybh) == dy ? (1.f - fy) : 0.f)
                      + ((y1 - ybh) == dy ? fy : 0.f);
            acc = fmaf(wgt, wdw[(cb + ch) * 9 + i3 * 3 + j], acc);
        }
        s_A[ch * 49 + h * 12 + dy * 4 + j] = acc;
    }
    __syncthreads();

    // ---- compute: thread = (chp = tid/20, run = tid%20), 2ch x 4r x 8px ----
    const int chp = tid / 20;
    const int run = tid - chp * 20;
    const int wq  = run * 8;

    int x0i[10]; float fx[10];
    #pragma unroll
    for (int j = 0; j < 10; j++) {
        float wx = (float)(wq + j) * WS;
        int x0 = (int)wx;
        fx[j]  = wx - (float)x0;
        x0i[j] = x0;
    }
    int rbh[4];
    #pragma unroll
    for (int hh = 0; hh < 4; hh++)
        rbh[hh] = (int)((h0 + hh) * HS) - rbase;

    float d0[4][8], d1[4][8];
    #pragma unroll
    for (int hh = 0; hh < 4; hh++)
        #pragma unroll
        for (int i = 0; i < 8; i++) { d0[hh][i] = 0.f; d1[hh][i] = 0.f; }

    #pragma unroll
    for (int r = 0; r < 5; r++) {
        const uint32_t* rowp = &s_px[(r * 16 + chp) * 84];
        float cx0[10], cx1[10];
        #pragma unroll
        for (int j = 0; j < 10; j++) {
            uint32_t wa = rowp[x0i[j]];
            uint32_t wb = rowp[x0i[j] + 1];      // ds_read2_b32 pair
            float a0 = unp_lo(wa), a1 = unp_lo(wb);
            float b0_ = unp_hi(wa), b1_ = unp_hi(wb);
            cx0[j] = fmaf(fx[j], a1 - a0, a0);
            cx1[j] = fmaf(fx[j], b1_ - b0_, b0_);
        }
        #pragma unroll
        for (int hh = 0; hh < 4; hh++) {
            int dyL = r - rbh[hh];
            if ((unsigned)dyL <= 2u) {
                const float* Aa = &s_A[(2 * chp) * 49 + hh * 12 + dyL * 4];
                const float* Ab = &s_A[(2 * chp + 1) * 49 + hh * 12 + dyL * 4];
                float a0 = Aa[0], a1 = Aa[1], a2 = Aa[2];
                float e0 = Ab[0], e1 = Ab[1], e2 = Ab[2];
                #pragma unroll
                for (int i = 0; i < 8; i++) {
                    d0[hh][i] = fmaf(a0, cx0[i],
                                fmaf(a1, cx0[i+1],
                                fmaf(a2, cx0[i+2], d0[hh][i])));
                    d1[hh][i] = fmaf(e0, cx1[i],
                                fmaf(e1, cx1[i+1],
                                fmaf(e2, cx1[i+2], d1[hh][i])));
                }
            }
        }
    }

    // ---- epilogue: per out-row, transpose via LDS, 64B/px coalesced store ----
    const int pxl  = tid >> 1;       // 0..159
    const int half = tid & 1;
    #pragma unroll
    for (int hh = 0; hh < 4; hh++) {
        __syncthreads();   // prev phase's coop readers done
        #pragma unroll
        for (int i = 0; i < 8; i++)
            s_out[(wq + i) * A_SOS + chp] = pack_bf2(d0[hh][i], d1[hh][i]);
        __syncthreads();
        uint4 v0 = *(const uint4*)&s_out[pxl * A_SOS + half * 8];
        uint4 v1 = *(const uint4*)&s_out[pxl * A_SOS + half * 8 + 4];
        size_t gpx = (size_t)bl * NPIX + (size_t)(h0 + hh) * UPW + pxl;
        uint32_t* gdst = (uint32_t*)(dwb + gpx * CIN + cb) + half * 8;
        *(uint4*)gdst       = v0;
        *(uint4*)(gdst + 4) = v1;
    }
}

// ======================= Kernel B: LDS-free MFMA GEMM =======================
// block 512 thr = 8 waves: 4 o32-tiles x 2 px-halves of a 128-px tile.
__global__ __launch_bounds__(512, 4) void pw_kernel(
    const __bf16* __restrict__ dwb,   // [bs,19200,256]
    const float* __restrict__ wpw,    // [128,256]
    float* __restrict__ out,          // [B,128,19200]
    int b0)
{
    const int tid  = threadIdx.x;
    const int tile = blockIdx.x;          // 0..149
    const int bl   = blockIdx.y;
    const int b    = b0 + bl;

    const int wave = tid >> 6, lane = tid & 63;
    const int quad = lane >> 4, l16 = lane & 15;
    const int o32  = (wave & 3) * 32;
    const int pg   = wave >> 2;           // 0..1

    floatx4 acc[2][4];
    #pragma unroll
    for (int a = 0; a < 2; a++)
        #pragma unroll
        for (int p = 0; p < 4; p++) acc[a][p] = (floatx4){0.f,0.f,0.f,0.f};

    const int pxb = tile * 128 + pg * 64;
    const __bf16* dwp = dwb + ((size_t)bl * NPIX + pxb) * CIN;
    const float* w0p = wpw + (size_t)(o32 + l16) * CIN + quad * 8;
    const float* w1p = w0p + 16 * CIN;

    // A-frag loader: 8 consecutive fp32 -> bf16x8
    #define LOAD_AF(dst, base, ck) { \
        float4 u = *(const float4*)((base) + (ck) * 32); \
        float4 v = *(const float4*)((base) + (ck) * 32 + 4); \
        dst = (bf16x8){(__bf16)u.x,(__bf16)u.y,(__bf16)u.z,(__bf16)u.w, \
                       (__bf16)v.x,(__bf16)v.y,(__bf16)v.z,(__bf16)v.w}; }

    bf16x8 af0, af1;
    LOAD_AF(af0, w0p, 0);
    LOAD_AF(af1, w1p, 0);

    #pragma unroll
    for (int ck = 0; ck < 8; ck++) {
        bf16x8 nf0, nf1;
        if (ck < 7) { LOAD_AF(nf0, w0p, ck + 1); LOAD_AF(nf1, w1p, ck + 1); }
        #pragma unroll
        for (int pt = 0; pt < 4; pt++) {
            bf16x8 bf = *(const bf16x8*)(dwp + (size_t)(pt * 16 + l16) * CIN
                                             + ck * 32 + quad * 8);
            acc[0][pt] = __builtin_amdgcn_mfma_f32_16x16x32_bf16(af0, bf, acc[0][pt], 0, 0, 0);
            acc[1][pt] = __builtin_amdgcn_mfma_f32_16x16x32_bf16(af1, bf, acc[1][pt], 0, 0, 0);
        }
        af0 = nf0; af1 = nf1;
    }

    // epilogue: D[row=quad*4+r][col=l16]
    float* ob = out + (size_t)b * COUT * NPIX + pxb;
    #pragma unroll
    for (int ot = 0; ot < 2; ot++)
        #pragma unroll
        for (int pt = 0; pt < 4; pt++)
            #pragma unroll
            for (int r = 0; r < 4; r++)
                ob[(size_t)(o32 + ot * 16 + quad * 4 + r) * NPIX
                   + pt * 16 + l16] = acc[ot][pt][r];
}

extern "C" void kernel_launch(void* const* d_in, const int* in_sizes, int n_in,
                              void* d_out, int out_size, void* d_ws, size_t ws_size,
                              hipStream_t stream) {
    const float* x   = (const float*)d_in[0];
    const float* wdw = (const float*)d_in[1];
    const float* wpw = (const float*)d_in[2];
    float* out = (float*)d_out;
    __bf16* dwb = (__bf16*)d_ws;

    int bs = 8;
    while (bs > 1 && (size_t)bs * CIN * NPIX * 2 > ws_size) bs >>= 1;

    for (int b0 = 0; b0 < 8; b0 += bs) {
        dim3 gA(30, CIN / 32, bs);     // 30 x 8 x bs
        dw_kernel<<<gA, A_NT, 0, stream>>>(x, wdw, dwb, b0);
        dim3 gB(NPIX / 128, bs);       // 150 x bs
        pw_kernel<<<gB, 512, 0, stream>>>(dwb, wpw, out, b0);
    }
}